// Round 2
// baseline (1028.741 us; speedup 1.0000x reference)
//
#include <hip/hip_runtime.h>
#include <cstdint>

// Problem constants (N=8192 nodes, K=64 neighbors incl. self, F=128 features)
#define N_NODES 8192
#define K_NB    64
#define F_DIM   128
#define SAMP_W  (2 * F_DIM + 1)          // 257 floats per sample row
#define RPB     32                       // adj rows per block (serial steps per WG)
#define NBLK    (N_NODES / RPB)          // 256 row blocks
#define CW      1024                     // column chunk width for phase 3
#define NCHUNK  (N_NODES / CW)           // 8 chunks -> 2048 WGs in p3 (8/CU)

typedef float v4f __attribute__((ext_vector_type(4)));

// Pack (ordinal, value): u64 atomicMax compares ordinal first (high word).
// ordinal = r*K + j + 1 (0 = "unset/carry"), unique -> value bits never decide.
static __device__ __forceinline__ unsigned long long pack_uv(unsigned int ord, float v) {
    return ((unsigned long long)ord << 32) | (unsigned long long)__float_as_uint(v);
}
static __device__ __forceinline__ float unpack_v(unsigned long long p) {
    return __uint_as_float((unsigned int)(p & 0xffffffffULL));
}

// ---------------------------------------------------------------------------
// samples: row (i*K + j) = [ emb[i] (128) | emb[c] (128) | sw[c] (1) ]
// Grid (N, 8): WG handles 8 rows of node i. All 8 neighbor gathers prefetched
// into registers before any store -> 8 loads in flight, no serial chain.
// Non-temporal stores: 539 MB pure write stream, keep it out of L2.
// ---------------------------------------------------------------------------
__global__ __launch_bounds__(256) void samples_kernel(
    const float* __restrict__ emb, const float* __restrict__ sw,
    const int* __restrict__ idx, float* __restrict__ out)
{
    const int i  = blockIdx.x;
    const int j0 = blockIdx.y * 8;
    const int t  = threadIdx.x;

    int c[8];
#pragma unroll
    for (int jj = 0; jj < 8; ++jj) {
        const int j = j0 + jj;
        c[jj] = (j < K_NB - 1) ? idx[i * (K_NB - 1) + j] : i;  // self last
    }
    const int rowbase = i * (K_NB * SAMP_W) + j0 * SAMP_W;     // < 2^27, int-safe

    if (t < F_DIM) {
        const float nd = emb[i * F_DIM + t];                   // node vec (reused)
#pragma unroll
        for (int jj = 0; jj < 8; ++jj) {
            const int base = rowbase + jj * SAMP_W;
            __builtin_nontemporal_store(nd, &out[base + t]);
            if (t == 0)
                __builtin_nontemporal_store(sw[c[jj]], &out[base + 2 * F_DIM]);
        }
    } else {
        float v[8];
#pragma unroll
        for (int jj = 0; jj < 8; ++jj)                         // 8 gathers in flight
            v[jj] = emb[c[jj] * F_DIM + (t - F_DIM)];
#pragma unroll
        for (int jj = 0; jj < 8; ++jj)
            __builtin_nontemporal_store(v[jj], &out[rowbase + jj * SAMP_W + t]);
    }
}

// ---------------------------------------------------------------------------
// P1: per row-block b, per column c: packed max-ordinal update (0 if none).
// LDS line of 8192 u64 (64 KB). RPB*64 = 2048 updates per block.
// ---------------------------------------------------------------------------
__global__ __launch_bounds__(256) void p1_kernel(
    const int* __restrict__ idx, const float* __restrict__ edge,
    unsigned long long* __restrict__ S)
{
    __shared__ unsigned long long line[N_NODES];      // 64 KB
    const int b = blockIdx.x;
    const int t = threadIdx.x;
    for (int k = t; k < N_NODES; k += 256) line[k] = 0ULL;
    __syncthreads();
    for (int u = t; u < RPB * K_NB; u += 256) {
        const int r = b * RPB + (u >> 6);
        const int j = u & 63;
        const int cc = (j < K_NB - 1) ? idx[r * (K_NB - 1) + j] : r;
        const float v = edge[r * K_NB + j];
        atomicMax(&line[cc], pack_uv((unsigned)(r * K_NB + j + 1), v));
    }
    __syncthreads();
    for (int k = t; k < N_NODES; k += 256) S[b * N_NODES + k] = line[k];
}

// ---------------------------------------------------------------------------
// P2: per column, forward scan over block summaries -> carry-in value per
// (block, column). Unrolled so the independent loads pipeline.
// ---------------------------------------------------------------------------
__global__ __launch_bounds__(256) void p2_kernel(
    const unsigned long long* __restrict__ S, float* __restrict__ carry)
{
    const int c = blockIdx.x * 256 + threadIdx.x;     // 8192 threads
    unsigned long long run = 0ULL;                    // value 0.0f initially
#pragma unroll 8
    for (int b = 0; b < NBLK; ++b) {
        carry[b * N_NODES + c] = unpack_v(run);       // state BEFORE block b
        const unsigned long long s = S[b * N_NODES + c];
        if (s != 0ULL) run = s;
    }
}

// ---------------------------------------------------------------------------
// P3: one WG per (32-row block, 1024-col chunk) = 2048 WGs (8/CU, 32 waves).
// Replay rows in order. Per row: atomics -> barrier -> line->regs (strided,
// 2-way = conflict-free) + prefetch next row's (idx,edge) -> barrier ->
// NT store from regs (overlaps next row's atomics).
// ---------------------------------------------------------------------------
__global__ __launch_bounds__(256) void p3_kernel(
    const int* __restrict__ idx, const float* __restrict__ edge,
    const float* __restrict__ carry, float* __restrict__ adj)
{
    __shared__ unsigned long long line[CW];           // 8 KB
    const int b  = blockIdx.x;                        // row block
    const int c0 = blockIdx.y * CW;                   // chunk base column
    const int t  = threadIdx.x;

    for (int k = t; k < CW; k += 256)
        line[k] = pack_uv(0u, carry[b * N_NODES + c0 + k]);

    // preload row 0's update
    int   cN = 0;
    float vN = 0.0f;
    {
        const int r0 = b * RPB;
        if (t < K_NB) {
            cN = (t < K_NB - 1) ? idx[r0 * (K_NB - 1) + t] : r0;
            vN = edge[r0 * K_NB + t];
        }
    }
    __syncthreads();

    for (int rr = 0; rr < RPB; ++rr) {
        const int r = b * RPB + rr;
        if (t < K_NB) {
            const unsigned cc = (unsigned)(cN - c0);
            if (cc < (unsigned)CW)
                atomicMax(&line[cc], pack_uv((unsigned)(r * K_NB + t + 1), vN));
        }
        __syncthreads();

        // line -> regs (lane-stride-1 over u64 = 2-way bank alias = free)
        const float x0 = unpack_v(line[t]);
        const float x1 = unpack_v(line[t + 256]);
        const float x2 = unpack_v(line[t + 512]);
        const float x3 = unpack_v(line[t + 768]);

        // prefetch next row's update while LDS reads drain
        if (rr + 1 < RPB && t < K_NB) {
            const int r2 = r + 1;
            cN = (t < K_NB - 1) ? idx[r2 * (K_NB - 1) + t] : r2;
            vN = edge[r2 * K_NB + t];
        }
        __syncthreads();   // own ds_reads complete before barrier -> regs safe

        // stores overlap next iteration's atomics (fire-and-forget)
        const int rowbase = r * N_NODES + c0;         // < 2^26, int-safe
        __builtin_nontemporal_store(x0, &adj[rowbase + t]);
        __builtin_nontemporal_store(x1, &adj[rowbase + t + 256]);
        __builtin_nontemporal_store(x2, &adj[rowbase + t + 512]);
        __builtin_nontemporal_store(x3, &adj[rowbase + t + 768]);
    }
}

// ---------------------------------------------------------------------------
// Launch. d_out = [samples (134,742,016 f32) | adj (67,108,864 f32)].
// Scratch (S: 16 MB, carry: 8 MB) lives at the FRONT of the samples region;
// samples_kernel runs LAST and overwrites it (stream-ordered, graph-safe) so
// we never depend on ws_size.
// ---------------------------------------------------------------------------
extern "C" void kernel_launch(void* const* d_in, const int* in_sizes, int n_in,
                              void* d_out, int out_size, void* d_ws, size_t ws_size,
                              hipStream_t stream)
{
    const float* emb  = (const float*)d_in[0];
    const float* sw   = (const float*)d_in[1];
    const int*   idx  = (const int*)d_in[2];
    const float* edge = (const float*)d_in[3];

    float* out     = (float*)d_out;
    float* samples = out;
    float* adj     = out + (size_t)N_NODES * K_NB * SAMP_W;

    unsigned long long* S = (unsigned long long*)d_out;                  // 16 MB
    float* carry = (float*)((char*)d_out + (size_t)NBLK * N_NODES * 8);  // 8 MB

    p1_kernel<<<NBLK, 256, 0, stream>>>(idx, edge, S);
    p2_kernel<<<N_NODES / 256, 256, 0, stream>>>(S, carry);
    p3_kernel<<<dim3(NBLK, NCHUNK), 256, 0, stream>>>(idx, edge, carry, adj);
    samples_kernel<<<dim3(N_NODES, 8), 256, 0, stream>>>(emb, sw, idx, samples);
}